// Round 3
// baseline (123.052 us; speedup 1.0000x reference)
//
#include <hip/hip_runtime.h>
#include <hip/hip_bf16.h>
#include <math.h>

#define N_TOK 4096
#define M_TOK 1024
#define DMODEL 512
#define NHEAD 8
#define DHEAD 64

typedef __attribute__((ext_vector_type(8))) short short8;
typedef __attribute__((ext_vector_type(4))) float f32x4;
typedef __attribute__((ext_vector_type(4))) float float4v;

static __device__ __forceinline__ short f2bf(float f) {
    union { float f; unsigned u; } v; v.f = f;
    unsigned r = v.u + 0x7fffu + ((v.u >> 16) & 1u);
    return (short)(r >> 16);
}

// ---------------------------------------------------------------------------
// Pack: fp32 -> bf16. Activations row-major; ALL weights stored TRANSPOSED
// B^T[n][k] so GEMM B-staging is a plain vector copy.
// ---------------------------------------------------------------------------
__global__ void pack_kernel(const float* __restrict__ xv, const float* __restrict__ xt,
                            const float* __restrict__ wq, const float* __restrict__ wk,
                            const float* __restrict__ wv, const float* __restrict__ wo,
                            short* __restrict__ xvb, short* __restrict__ xtb,
                            short* __restrict__ wqb, short* __restrict__ wkb,
                            short* __restrict__ wvb, short* __restrict__ wob) {
    int idx = blockIdx.x * 256 + threadIdx.x;
    int stride = gridDim.x * 256;
    const int CXV = N_TOK * DMODEL / 8;
    const int CXT = M_TOK * DMODEL / 8;
    const int NW  = DMODEL * DMODEL;
    for (int c = idx; c < CXV; c += stride) {
        float4v f0 = *(const float4v*)&xv[c * 8];
        float4v f1 = *(const float4v*)&xv[c * 8 + 4];
        short8 o;
        #pragma unroll
        for (int j = 0; j < 4; j++) { o[j] = f2bf(f0[j]); o[j + 4] = f2bf(f1[j]); }
        *(short8*)&xvb[c * 8] = o;
    }
    for (int c = idx; c < CXT; c += stride) {
        float4v f0 = *(const float4v*)&xt[c * 8];
        float4v f1 = *(const float4v*)&xt[c * 8 + 4];
        short8 o;
        #pragma unroll
        for (int j = 0; j < 4; j++) { o[j] = f2bf(f0[j]); o[j + 4] = f2bf(f1[j]); }
        *(short8*)&xtb[c * 8] = o;
    }
    for (int i = idx; i < NW; i += stride) {
        int n = i >> 9;          // output col index
        int k = i & 511;         // contraction dim d
        int h = n >> 6, e = n & 63;
        int src = h * (DMODEL * DHEAD) + k * DHEAD + e;
        wqb[i] = f2bf(wq[src]);
        wkb[i] = f2bf(wk[src]);
        wvb[i] = f2bf(wv[src]);
        wob[i] = f2bf(wo[k * DMODEL + n]);
    }
}

// ---------------------------------------------------------------------------
// GEMM: C[M][512] = A[M][512] * B(^T stored), bf16 in, 64x64 tile, BK=64.
// MODE 0: bf16 row-major out. MODE 1: fp32 out + positional encoding (table).
// ---------------------------------------------------------------------------
template<int MODE>
__global__ __launch_bounds__(256) void gemm64(const short* __restrict__ A,
                                              const short* __restrict__ BT,
                                              void* __restrict__ Cout) {
    __shared__ __align__(16) short As[64][72];
    __shared__ __align__(16) short Bs[64][72];
    __shared__ float ifreq[256];
    int m0 = blockIdx.x * 64;
    int n0 = blockIdx.y * 64;
    int t = threadIdx.x;
    int lane = t & 63, w = t >> 6;
    int wr = w >> 1, wc = w & 1;
    int l15 = lane & 15, g = lane >> 4;

    if (MODE == 1) ifreq[t] = expf(-(float)t * (9.210340371976184f / 512.0f));

    f32x4 acc[2][2] = {};
    for (int kk = 0; kk < DMODEL; kk += 64) {
        {
            int row = t >> 2, c0 = (t & 3) * 16;
            *(short8*)&As[row][c0]     = *(const short8*)&A[(m0 + row) * DMODEL + kk + c0];
            *(short8*)&As[row][c0 + 8] = *(const short8*)&A[(m0 + row) * DMODEL + kk + c0 + 8];
            *(short8*)&Bs[row][c0]     = *(const short8*)&BT[(n0 + row) * DMODEL + kk + c0];
            *(short8*)&Bs[row][c0 + 8] = *(const short8*)&BT[(n0 + row) * DMODEL + kk + c0 + 8];
        }
        __syncthreads();
        #pragma unroll
        for (int ks = 0; ks < 2; ks++) {
            short8 a[2], b[2];
            #pragma unroll
            for (int fr = 0; fr < 2; fr++) a[fr] = *(short8*)&As[wr * 32 + fr * 16 + l15][ks * 32 + g * 8];
            #pragma unroll
            for (int fc = 0; fc < 2; fc++) b[fc] = *(short8*)&Bs[wc * 32 + fc * 16 + l15][ks * 32 + g * 8];
            #pragma unroll
            for (int fr = 0; fr < 2; fr++)
                #pragma unroll
                for (int fc = 0; fc < 2; fc++)
                    acc[fr][fc] = __builtin_amdgcn_mfma_f32_16x16x32_bf16(a[fr], b[fc], acc[fr][fc], 0, 0, 0);
        }
        __syncthreads();
    }
    #pragma unroll
    for (int fr = 0; fr < 2; fr++)
        #pragma unroll
        for (int fc = 0; fc < 2; fc++)
            #pragma unroll
            for (int r = 0; r < 4; r++) {
                int row = m0 + wr * 32 + fr * 16 + g * 4 + r;
                int col = n0 + wc * 32 + fc * 16 + l15;
                float v = acc[fr][fc][r];
                if (MODE == 1) {
                    float x = (float)row * ifreq[col >> 1];
                    float pe = (col & 1) ? cosf(x) : sinf(x);
                    ((float*)Cout)[row * DMODEL + col] = v + pe;
                } else {
                    ((short*)Cout)[row * DMODEL + col] = f2bf(v);
                }
            }
}

// ---------------------------------------------------------------------------
// K and V projections in one kernel (256 blocks). K -> row-major [m][512],
// V -> transposed V^T[d][1024].
// ---------------------------------------------------------------------------
__global__ __launch_bounds__(256) void gemmKV(const short* __restrict__ A,
                                              const short* __restrict__ BKt,
                                              const short* __restrict__ BVt,
                                              short* __restrict__ Ck,
                                              short* __restrict__ CvT) {
    __shared__ __align__(16) short As[64][72];
    __shared__ __align__(16) short Bs[64][72];
    bool isV = blockIdx.y >= 8;
    const short* BT = isV ? BVt : BKt;
    int m0 = blockIdx.x * 64;
    int n0 = (blockIdx.y & 7) * 64;
    int t = threadIdx.x;
    int lane = t & 63, w = t >> 6;
    int wr = w >> 1, wc = w & 1;
    int l15 = lane & 15, g = lane >> 4;

    f32x4 acc[2][2] = {};
    for (int kk = 0; kk < DMODEL; kk += 64) {
        {
            int row = t >> 2, c0 = (t & 3) * 16;
            *(short8*)&As[row][c0]     = *(const short8*)&A[(m0 + row) * DMODEL + kk + c0];
            *(short8*)&As[row][c0 + 8] = *(const short8*)&A[(m0 + row) * DMODEL + kk + c0 + 8];
            *(short8*)&Bs[row][c0]     = *(const short8*)&BT[(n0 + row) * DMODEL + kk + c0];
            *(short8*)&Bs[row][c0 + 8] = *(const short8*)&BT[(n0 + row) * DMODEL + kk + c0 + 8];
        }
        __syncthreads();
        #pragma unroll
        for (int ks = 0; ks < 2; ks++) {
            short8 a[2], b[2];
            #pragma unroll
            for (int fr = 0; fr < 2; fr++) a[fr] = *(short8*)&As[wr * 32 + fr * 16 + l15][ks * 32 + g * 8];
            #pragma unroll
            for (int fc = 0; fc < 2; fc++) b[fc] = *(short8*)&Bs[wc * 32 + fc * 16 + l15][ks * 32 + g * 8];
            #pragma unroll
            for (int fr = 0; fr < 2; fr++)
                #pragma unroll
                for (int fc = 0; fc < 2; fc++)
                    acc[fr][fc] = __builtin_amdgcn_mfma_f32_16x16x32_bf16(a[fr], b[fc], acc[fr][fc], 0, 0, 0);
        }
        __syncthreads();
    }
    #pragma unroll
    for (int fr = 0; fr < 2; fr++)
        #pragma unroll
        for (int fc = 0; fc < 2; fc++)
            #pragma unroll
            for (int r = 0; r < 4; r++) {
                int row = m0 + wr * 32 + fr * 16 + g * 4 + r;
                int col = n0 + wc * 32 + fc * 16 + l15;
                float v = acc[fr][fc][r];
                if (isV) CvT[col * M_TOK + row] = f2bf(v);
                else     Ck[row * DMODEL + col] = f2bf(v);
            }
}

// ---------------------------------------------------------------------------
// Attention v3: block = 16 q-rows x 1 head, 4 waves each owning a disjoint
// 256-key range (grid 256x8 = 2048 blocks -> 8192 waves = 100% occupancy).
// Single-pass exp-sum softmax => partial (acc, rsum) merge is a plain sum.
// K / V^T fragments direct from global (L2-resident). No in-loop barriers.
// ---------------------------------------------------------------------------
__global__ __launch_bounds__(256, 8) void attn_kernel(const short* __restrict__ Qb,
                                                      const short* __restrict__ Kb,
                                                      const short* __restrict__ VbT,
                                                      short* __restrict__ Yb) {
    // Ps: [2 parity][4 waves][16 q][40 keys] shorts = 10240 B
    // merge: [3 waves][64 lanes][20 floats]         = 15360 B  (aliased, barrier-protected)
    __shared__ __align__(16) char smem[15360];
    short (*Ps)[4][16][40] = (short(*)[4][16][40])smem;
    float* Ls = (float*)smem;

    int h = blockIdx.y;
    int n0 = blockIdx.x * 16;
    int t = threadIdx.x;
    int lane = t & 63, w = t >> 6;
    int l15 = lane & 15, g = lane >> 4;

    const short* qrow = Qb + (n0 + l15) * DMODEL + h * DHEAD;
    short8 qa0 = *(const short8*)(qrow + g * 8);
    short8 qa1 = *(const short8*)(qrow + 32 + g * 8);

    const short* Kh = Kb + h * DHEAD + (w * 256) * DMODEL;        // this wave's keys
    const short* Vh = VbT + (h * DHEAD) * M_TOK + w * 256;

    f32x4 acc[4] = {};
    f32x4 rsum = {};

    for (int kb2 = 0; kb2 < 4; kb2++) {
        #pragma unroll
        for (int par = 0; par < 2; par++) {
            int kb = kb2 * 64 + par * 32;
            #pragma unroll
            for (int kt = 0; kt < 2; kt++) {
                const short* krow = Kh + (kb + kt * 16 + l15) * DMODEL;
                f32x4 e = {};
                short8 kf0 = *(const short8*)(krow + g * 8);
                short8 kf1 = *(const short8*)(krow + 32 + g * 8);
                e = __builtin_amdgcn_mfma_f32_16x16x32_bf16(qa0, kf0, e, 0, 0, 0);
                e = __builtin_amdgcn_mfma_f32_16x16x32_bf16(qa1, kf1, e, 0, 0, 0);
                #pragma unroll
                for (int r = 0; r < 4; r++) {
                    float p = expf(e[r]);
                    rsum[r] += p;
                    Ps[par][w][g * 4 + r][kt * 16 + l15] = f2bf(p);
                }
            }
            short8 pa = *(short8*)&Ps[par][w][l15][g * 8];
            #pragma unroll
            for (int nt = 0; nt < 4; nt++) {
                short8 vf = *(const short8*)(Vh + (nt * 16 + l15) * M_TOK + kb + g * 8);
                acc[nt] = __builtin_amdgcn_mfma_f32_16x16x32_bf16(pa, vf, acc[nt], 0, 0, 0);
            }
        }
    }

    __syncthreads();              // all waves done with Ps before aliasing as merge buffer
    if (w > 0) {
        float* dst = Ls + ((w - 1) * 64 + lane) * 20;
        #pragma unroll
        for (int nt = 0; nt < 4; nt++) *(f32x4*)(dst + nt * 4) = acc[nt];
        *(f32x4*)(dst + 16) = rsum;
    }
    __syncthreads();
    if (w == 0) {
        #pragma unroll
        for (int ww = 0; ww < 3; ww++) {
            const float* src = Ls + (ww * 64 + lane) * 20;
            #pragma unroll
            for (int nt = 0; nt < 4; nt++) acc[nt] += *(const f32x4*)(src + nt * 4);
            rsum += *(const f32x4*)(src + 16);
        }
        #pragma unroll
        for (int r = 0; r < 4; r++) {
            float s = rsum[r];
            s += __shfl_xor(s, 1);
            s += __shfl_xor(s, 2);
            s += __shfl_xor(s, 4);
            s += __shfl_xor(s, 8);
            rsum[r] = s;
        }
        #pragma unroll
        for (int nt = 0; nt < 4; nt++)
            #pragma unroll
            for (int r = 0; r < 4; r++) {
                float y = acc[nt][r] / rsum[r];
                Yb[(n0 + g * 4 + r) * DMODEL + h * DHEAD + nt * 16 + l15] = f2bf(y);
            }
    }
}

// ---------------------------------------------------------------------------
extern "C" void kernel_launch(void* const* d_in, const int* in_sizes, int n_in,
                              void* d_out, int out_size, void* d_ws, size_t ws_size,
                              hipStream_t stream) {
    const float* xv = (const float*)d_in[0];
    const float* xt = (const float*)d_in[1];
    const float* wq = (const float*)d_in[2];
    const float* wk = (const float*)d_in[3];
    const float* wv = (const float*)d_in[4];
    const float* wo = (const float*)d_in[5];

    short* xvb = (short*)d_ws;              // 4096*512
    short* xtb = xvb + N_TOK * DMODEL;      // 1024*512
    short* wqb = xtb + M_TOK * DMODEL;      // 512*512 (B^T)
    short* wkb = wqb + DMODEL * DMODEL;
    short* wvb = wkb + DMODEL * DMODEL;
    short* wob = wvb + DMODEL * DMODEL;
    short* qb  = wob + DMODEL * DMODEL;     // 4096*512
    short* kbm = qb  + N_TOK * DMODEL;      // 1024*512
    short* vbt = kbm + M_TOK * DMODEL;      // 512*1024 (V^T)
    short* yb  = vbt + M_TOK * DMODEL;      // 4096*512

    pack_kernel<<<1024, 256, 0, stream>>>(xv, xt, wq, wk, wv, wo,
                                          xvb, xtb, wqb, wkb, wvb, wob);
    gemm64<0><<<dim3(N_TOK / 64, 8), 256, 0, stream>>>(xvb, wqb, qb);
    gemmKV<<<dim3(M_TOK / 64, 16), 256, 0, stream>>>(xtb, wkb, wvb, kbm, vbt);
    attn_kernel<<<dim3(N_TOK / 16, 8), 256, 0, stream>>>(qb, kbm, vbt, yb);
    gemm64<1><<<dim3(N_TOK / 64, 8), 256, 0, stream>>>(yb, wob, d_out);
}

// Round 4
// 104.328 us; speedup vs baseline: 1.1795x; 1.1795x over previous
//
#include <hip/hip_runtime.h>
#include <hip/hip_bf16.h>
#include <math.h>

#define N_TOK 4096
#define M_TOK 1024
#define DMODEL 512
#define NHEAD 8
#define DHEAD 64

typedef __attribute__((ext_vector_type(8))) short short8;
typedef __attribute__((ext_vector_type(4))) float f32x4;
typedef __attribute__((ext_vector_type(4))) float float4v;

static __device__ __forceinline__ short f2bf(float f) {
    union { float f; unsigned u; } v; v.f = f;
    unsigned r = v.u + 0x7fffu + ((v.u >> 16) & 1u);
    return (short)(r >> 16);
}

// ---------------------------------------------------------------------------
// Pack: fp32 -> bf16. Activations row-major; ALL weights stored TRANSPOSED
// B^T[n][k] so GEMM B-staging is a plain vector copy.
// ---------------------------------------------------------------------------
__global__ void pack_kernel(const float* __restrict__ xv, const float* __restrict__ xt,
                            const float* __restrict__ wq, const float* __restrict__ wk,
                            const float* __restrict__ wv, const float* __restrict__ wo,
                            short* __restrict__ xvb, short* __restrict__ xtb,
                            short* __restrict__ wqb, short* __restrict__ wkb,
                            short* __restrict__ wvb, short* __restrict__ wob) {
    int idx = blockIdx.x * 256 + threadIdx.x;
    int stride = gridDim.x * 256;
    const int CXV = N_TOK * DMODEL / 8;
    const int CXT = M_TOK * DMODEL / 8;
    const int NW  = DMODEL * DMODEL;
    for (int c = idx; c < CXV; c += stride) {
        float4v f0 = *(const float4v*)&xv[c * 8];
        float4v f1 = *(const float4v*)&xv[c * 8 + 4];
        short8 o;
        #pragma unroll
        for (int j = 0; j < 4; j++) { o[j] = f2bf(f0[j]); o[j + 4] = f2bf(f1[j]); }
        *(short8*)&xvb[c * 8] = o;
    }
    for (int c = idx; c < CXT; c += stride) {
        float4v f0 = *(const float4v*)&xt[c * 8];
        float4v f1 = *(const float4v*)&xt[c * 8 + 4];
        short8 o;
        #pragma unroll
        for (int j = 0; j < 4; j++) { o[j] = f2bf(f0[j]); o[j + 4] = f2bf(f1[j]); }
        *(short8*)&xtb[c * 8] = o;
    }
    for (int i = idx; i < NW; i += stride) {
        int n = i >> 9;          // output col index
        int k = i & 511;         // contraction dim d
        int h = n >> 6, e = n & 63;
        int src = h * (DMODEL * DHEAD) + k * DHEAD + e;
        wqb[i] = f2bf(wq[src]);
        wkb[i] = f2bf(wk[src]);
        wvb[i] = f2bf(wv[src]);
        wob[i] = f2bf(wo[k * DMODEL + n]);
    }
}

// ---------------------------------------------------------------------------
// Q, K, V projections in ONE launch. grid (96, 8):
//   bx <  64: Q tile (A=xv),  row-major out
//   bx < 80 : K tile (A=xt),  row-major out
//   else    : V tile (A=xt),  TRANSPOSED out V^T[d][1024]
// 64x64 tile, BK=64, 4 waves.
// ---------------------------------------------------------------------------
__global__ __launch_bounds__(256) void gemmQKV(const short* __restrict__ xvb,
                                               const short* __restrict__ xtb,
                                               const short* __restrict__ wqb,
                                               const short* __restrict__ wkb,
                                               const short* __restrict__ wvb,
                                               short* __restrict__ qb,
                                               short* __restrict__ kbm,
                                               short* __restrict__ vbt) {
    __shared__ __align__(16) short As[64][72];
    __shared__ __align__(16) short Bs[64][72];
    int bx = blockIdx.x;
    const short* A; const short* BT; short* C; int m0; bool transC;
    if (bx < 64)      { A = xvb; BT = wqb; C = qb;  m0 = bx * 64;        transC = false; }
    else if (bx < 80) { A = xtb; BT = wkb; C = kbm; m0 = (bx - 64) * 64; transC = false; }
    else              { A = xtb; BT = wvb; C = vbt; m0 = (bx - 80) * 64; transC = true;  }
    int n0 = blockIdx.y * 64;
    int t = threadIdx.x;
    int lane = t & 63, w = t >> 6;
    int wr = w >> 1, wc = w & 1;
    int l15 = lane & 15, g = lane >> 4;

    f32x4 acc[2][2] = {};
    for (int kk = 0; kk < DMODEL; kk += 64) {
        {
            int row = t >> 2, c0 = (t & 3) * 16;
            *(short8*)&As[row][c0]     = *(const short8*)&A[(m0 + row) * DMODEL + kk + c0];
            *(short8*)&As[row][c0 + 8] = *(const short8*)&A[(m0 + row) * DMODEL + kk + c0 + 8];
            *(short8*)&Bs[row][c0]     = *(const short8*)&BT[(n0 + row) * DMODEL + kk + c0];
            *(short8*)&Bs[row][c0 + 8] = *(const short8*)&BT[(n0 + row) * DMODEL + kk + c0 + 8];
        }
        __syncthreads();
        #pragma unroll
        for (int ks = 0; ks < 2; ks++) {
            short8 a[2], b[2];
            #pragma unroll
            for (int fr = 0; fr < 2; fr++) a[fr] = *(short8*)&As[wr * 32 + fr * 16 + l15][ks * 32 + g * 8];
            #pragma unroll
            for (int fc = 0; fc < 2; fc++) b[fc] = *(short8*)&Bs[wc * 32 + fc * 16 + l15][ks * 32 + g * 8];
            #pragma unroll
            for (int fr = 0; fr < 2; fr++)
                #pragma unroll
                for (int fc = 0; fc < 2; fc++)
                    acc[fr][fc] = __builtin_amdgcn_mfma_f32_16x16x32_bf16(a[fr], b[fc], acc[fr][fc], 0, 0, 0);
        }
        __syncthreads();
    }
    #pragma unroll
    for (int fr = 0; fr < 2; fr++)
        #pragma unroll
        for (int fc = 0; fc < 2; fc++)
            #pragma unroll
            for (int r = 0; r < 4; r++) {
                int row = m0 + wr * 32 + fr * 16 + g * 4 + r;
                int col = n0 + wc * 32 + fc * 16 + l15;
                float v = acc[fr][fc][r];
                if (transC) C[col * M_TOK + row] = f2bf(v);
                else        C[row * DMODEL + col] = f2bf(v);
            }
}

// ---------------------------------------------------------------------------
// Final GEMM: out = Y * Wout^T(stored) + PE, fp32 out. 64x64 tile.
// ---------------------------------------------------------------------------
__global__ __launch_bounds__(256) void gemmOut(const short* __restrict__ A,
                                               const short* __restrict__ BT,
                                               float* __restrict__ Cout) {
    __shared__ __align__(16) short As[64][72];
    __shared__ __align__(16) short Bs[64][72];
    __shared__ float ifreq[256];
    int m0 = blockIdx.x * 64;
    int n0 = blockIdx.y * 64;
    int t = threadIdx.x;
    int lane = t & 63, w = t >> 6;
    int wr = w >> 1, wc = w & 1;
    int l15 = lane & 15, g = lane >> 4;

    ifreq[t] = expf(-(float)t * (9.210340371976184f / 512.0f));

    f32x4 acc[2][2] = {};
    for (int kk = 0; kk < DMODEL; kk += 64) {
        {
            int row = t >> 2, c0 = (t & 3) * 16;
            *(short8*)&As[row][c0]     = *(const short8*)&A[(m0 + row) * DMODEL + kk + c0];
            *(short8*)&As[row][c0 + 8] = *(const short8*)&A[(m0 + row) * DMODEL + kk + c0 + 8];
            *(short8*)&Bs[row][c0]     = *(const short8*)&BT[(n0 + row) * DMODEL + kk + c0];
            *(short8*)&Bs[row][c0 + 8] = *(const short8*)&BT[(n0 + row) * DMODEL + kk + c0 + 8];
        }
        __syncthreads();
        #pragma unroll
        for (int ks = 0; ks < 2; ks++) {
            short8 a[2], b[2];
            #pragma unroll
            for (int fr = 0; fr < 2; fr++) a[fr] = *(short8*)&As[wr * 32 + fr * 16 + l15][ks * 32 + g * 8];
            #pragma unroll
            for (int fc = 0; fc < 2; fc++) b[fc] = *(short8*)&Bs[wc * 32 + fc * 16 + l15][ks * 32 + g * 8];
            #pragma unroll
            for (int fr = 0; fr < 2; fr++)
                #pragma unroll
                for (int fc = 0; fc < 2; fc++)
                    acc[fr][fc] = __builtin_amdgcn_mfma_f32_16x16x32_bf16(a[fr], b[fc], acc[fr][fc], 0, 0, 0);
        }
        __syncthreads();
    }
    #pragma unroll
    for (int fr = 0; fr < 2; fr++)
        #pragma unroll
        for (int fc = 0; fc < 2; fc++)
            #pragma unroll
            for (int r = 0; r < 4; r++) {
                int row = m0 + wr * 32 + fr * 16 + g * 4 + r;
                int col = n0 + wc * 32 + fc * 16 + l15;
                float x = (float)row * ifreq[col >> 1];
                float pe = (col & 1) ? cosf(x) : sinf(x);
                Cout[row * DMODEL + col] = acc[fr][fc][r] + pe;
            }
}

// ---------------------------------------------------------------------------
// Attention v4: block = 32 q-rows x head; 4 waves = q-split 2 x key-split 2
// (each wave: 16 q x 512 keys). Grid (128,8)=1024 blocks.
// K register-double-buffered (prefetch next iter); V loaded at iter top so
// L2 latency hides under QK-MFMA + exp + P LDS round-trip. No in-loop
// barriers. Single-pass exp-sum softmax; 2-way key merge = plain sum.
// ---------------------------------------------------------------------------
#define LOADK(kb, k0a, k0b, k1a, k1b) { \
    const short* kr0 = Kh + ((kb) + l15) * DMODEL; \
    const short* kr1 = Kh + ((kb) + 16 + l15) * DMODEL; \
    k0a = *(const short8*)(kr0 + g * 8); \
    k0b = *(const short8*)(kr0 + 32 + g * 8); \
    k1a = *(const short8*)(kr1 + g * 8); \
    k1b = *(const short8*)(kr1 + 32 + g * 8); }

#define PROC(k0a, k0b, k1a, k1b, kb, par) { \
    short8 vf0 = *(const short8*)(Vh + (l15) * M_TOK + (kb) + g * 8); \
    short8 vf1 = *(const short8*)(Vh + (16 + l15) * M_TOK + (kb) + g * 8); \
    short8 vf2 = *(const short8*)(Vh + (32 + l15) * M_TOK + (kb) + g * 8); \
    short8 vf3 = *(const short8*)(Vh + (48 + l15) * M_TOK + (kb) + g * 8); \
    f32x4 e0 = {}, e1 = {}; \
    e0 = __builtin_amdgcn_mfma_f32_16x16x32_bf16(qa0, k0a, e0, 0, 0, 0); \
    e0 = __builtin_amdgcn_mfma_f32_16x16x32_bf16(qa1, k0b, e0, 0, 0, 0); \
    e1 = __builtin_amdgcn_mfma_f32_16x16x32_bf16(qa0, k1a, e1, 0, 0, 0); \
    e1 = __builtin_amdgcn_mfma_f32_16x16x32_bf16(qa1, k1b, e1, 0, 0, 0); \
    _Pragma("unroll") \
    for (int r = 0; r < 4; r++) { \
        float p0 = exp2f(e0[r] * 1.44269504f); \
        float p1 = exp2f(e1[r] * 1.44269504f); \
        rsum[r] += p0 + p1; \
        Ps[w][par][g * 4 + r][l15] = f2bf(p0); \
        Ps[w][par][g * 4 + r][16 + l15] = f2bf(p1); \
    } \
    short8 pa = *(short8*)&Ps[w][par][l15][g * 8]; \
    acc[0] = __builtin_amdgcn_mfma_f32_16x16x32_bf16(pa, vf0, acc[0], 0, 0, 0); \
    acc[1] = __builtin_amdgcn_mfma_f32_16x16x32_bf16(pa, vf1, acc[1], 0, 0, 0); \
    acc[2] = __builtin_amdgcn_mfma_f32_16x16x32_bf16(pa, vf2, acc[2], 0, 0, 0); \
    acc[3] = __builtin_amdgcn_mfma_f32_16x16x32_bf16(pa, vf3, acc[3], 0, 0, 0); }

__global__ __launch_bounds__(256, 4) void attn_kernel(const short* __restrict__ Qb,
                                                      const short* __restrict__ Kb,
                                                      const short* __restrict__ VbT,
                                                      short* __restrict__ Yb) {
    __shared__ __align__(16) short Ps[4][2][16][40];   // 10240 B
    float* Ls = (float*)Ps;                            // merge buffer (aliased, barriered)

    int h = blockIdx.y;
    int t = threadIdx.x;
    int lane = t & 63, w = t >> 6;
    int qh = w & 1, ks = w >> 1;
    int n0 = blockIdx.x * 32 + qh * 16;
    int l15 = lane & 15, g = lane >> 4;

    const short* qrow = Qb + (n0 + l15) * DMODEL + h * DHEAD;
    short8 qa0 = *(const short8*)(qrow + g * 8);
    short8 qa1 = *(const short8*)(qrow + 32 + g * 8);

    const short* Kh = Kb + h * DHEAD + (ks * 512) * DMODEL;
    const short* Vh = VbT + (h * DHEAD) * M_TOK + ks * 512;

    f32x4 acc[4] = {};
    f32x4 rsum = {};

    short8 ka0a, ka0b, ka1a, ka1b, kb0a, kb0b, kb1a, kb1b;
    LOADK(0, ka0a, ka0b, ka1a, ka1b);
    #pragma unroll
    for (int it = 0; it < 16; it += 2) {
        LOADK((it + 1) * 32, kb0a, kb0b, kb1a, kb1b);
        PROC(ka0a, ka0b, ka1a, ka1b, it * 32, 0);
        if (it < 14) LOADK((it + 2) * 32, ka0a, ka0b, ka1a, ka1b);
        PROC(kb0a, kb0b, kb1a, kb1b, (it + 1) * 32, 1);
    }

    __syncthreads();             // everyone done with Ps
    if (ks == 1) {
        float* dst = Ls + (qh * 64 + lane) * 20;
        #pragma unroll
        for (int nt = 0; nt < 4; nt++) *(f32x4*)(dst + nt * 4) = acc[nt];
        *(f32x4*)(dst + 16) = rsum;
    }
    __syncthreads();
    if (ks == 0) {
        const float* src = Ls + (qh * 64 + lane) * 20;
        #pragma unroll
        for (int nt = 0; nt < 4; nt++) acc[nt] += *(const f32x4*)(src + nt * 4);
        rsum += *(const f32x4*)(src + 16);
        #pragma unroll
        for (int r = 0; r < 4; r++) {
            float s = rsum[r];
            s += __shfl_xor(s, 1);
            s += __shfl_xor(s, 2);
            s += __shfl_xor(s, 4);
            s += __shfl_xor(s, 8);
            rsum[r] = s;
        }
        #pragma unroll
        for (int nt = 0; nt < 4; nt++)
            #pragma unroll
            for (int r = 0; r < 4; r++) {
                float y = acc[nt][r] / rsum[r];
                Yb[(n0 + g * 4 + r) * DMODEL + h * DHEAD + nt * 16 + l15] = f2bf(y);
            }
    }
}

// ---------------------------------------------------------------------------
extern "C" void kernel_launch(void* const* d_in, const int* in_sizes, int n_in,
                              void* d_out, int out_size, void* d_ws, size_t ws_size,
                              hipStream_t stream) {
    const float* xv = (const float*)d_in[0];
    const float* xt = (const float*)d_in[1];
    const float* wq = (const float*)d_in[2];
    const float* wk = (const float*)d_in[3];
    const float* wv = (const float*)d_in[4];
    const float* wo = (const float*)d_in[5];

    short* xvb = (short*)d_ws;              // 4096*512
    short* xtb = xvb + N_TOK * DMODEL;      // 1024*512
    short* wqb = xtb + M_TOK * DMODEL;      // 512*512 (B^T)
    short* wkb = wqb + DMODEL * DMODEL;
    short* wvb = wkb + DMODEL * DMODEL;
    short* wob = wvb + DMODEL * DMODEL;
    short* qb  = wob + DMODEL * DMODEL;     // 4096*512
    short* kbm = qb  + N_TOK * DMODEL;      // 1024*512
    short* vbt = kbm + M_TOK * DMODEL;      // 512*1024 (V^T)
    short* yb  = vbt + M_TOK * DMODEL;      // 4096*512

    pack_kernel<<<1024, 256, 0, stream>>>(xv, xt, wq, wk, wv, wo,
                                          xvb, xtb, wqb, wkb, wvb, wob);
    gemmQKV<<<dim3(96, 8), 256, 0, stream>>>(xvb, xtb, wqb, wkb, wvb, qb, kbm, vbt);
    attn_kernel<<<dim3(N_TOK / 32, 8), 256, 0, stream>>>(qb, kbm, vbt, yb);
    gemmOut<<<dim3(N_TOK / 64, 8), 256, 0, stream>>>(yb, wob, (float*)d_out);
}

// Round 5
// 61.860 us; speedup vs baseline: 1.9892x; 1.6865x over previous
//
#include <hip/hip_runtime.h>
#include <hip/hip_bf16.h>
#include <math.h>

#define N_TOK 4096
#define M_TOK 1024
#define DMODEL 512
#define NHEAD 8
#define DHEAD 64

typedef __attribute__((ext_vector_type(8))) short short8;
typedef __attribute__((ext_vector_type(4))) float f32x4;
typedef __attribute__((ext_vector_type(4))) float float4v;

static __device__ __forceinline__ short f2bf(float f) {
    union { float f; unsigned u; } v; v.f = f;
    unsigned r = v.u + 0x7fffu + ((v.u >> 16) & 1u);
    return (short)(r >> 16);
}

#define GLOAD_LDS16(g, l) __builtin_amdgcn_global_load_lds( \
    (const __attribute__((address_space(1))) void*)(g), \
    (__attribute__((address_space(3))) void*)(l), 16, 0, 0)

// ---------------------------------------------------------------------------
// Pack: fp32 -> bf16. Weights stored TRANSPOSED B^T[n][k].
// ---------------------------------------------------------------------------
__global__ void pack_kernel(const float* __restrict__ xv, const float* __restrict__ xt,
                            const float* __restrict__ wq, const float* __restrict__ wk,
                            const float* __restrict__ wv, const float* __restrict__ wo,
                            short* __restrict__ xvb, short* __restrict__ xtb,
                            short* __restrict__ wqb, short* __restrict__ wkb,
                            short* __restrict__ wvb, short* __restrict__ wob) {
    int idx = blockIdx.x * 256 + threadIdx.x;
    int stride = gridDim.x * 256;
    const int CXV = N_TOK * DMODEL / 8;
    const int CXT = M_TOK * DMODEL / 8;
    const int NW  = DMODEL * DMODEL;
    for (int c = idx; c < CXV; c += stride) {
        float4v f0 = *(const float4v*)&xv[c * 8];
        float4v f1 = *(const float4v*)&xv[c * 8 + 4];
        short8 o;
        #pragma unroll
        for (int j = 0; j < 4; j++) { o[j] = f2bf(f0[j]); o[j + 4] = f2bf(f1[j]); }
        *(short8*)&xvb[c * 8] = o;
    }
    for (int c = idx; c < CXT; c += stride) {
        float4v f0 = *(const float4v*)&xt[c * 8];
        float4v f1 = *(const float4v*)&xt[c * 8 + 4];
        short8 o;
        #pragma unroll
        for (int j = 0; j < 4; j++) { o[j] = f2bf(f0[j]); o[j + 4] = f2bf(f1[j]); }
        *(short8*)&xtb[c * 8] = o;
    }
    for (int i = idx; i < NW; i += stride) {
        int n = i >> 9;
        int k = i & 511;
        int h = n >> 6, e = n & 63;
        int src = h * (DMODEL * DHEAD) + k * DHEAD + e;
        wqb[i] = f2bf(wq[src]);
        wkb[i] = f2bf(wk[src]);
        wvb[i] = f2bf(wv[src]);
        wob[i] = f2bf(wo[k * DMODEL + n]);
    }
}

// ---------------------------------------------------------------------------
// Q, K, V projections in ONE launch. grid (96, 8). 64x64 tile, BK=64.
// ---------------------------------------------------------------------------
__global__ __launch_bounds__(256) void gemmQKV(const short* __restrict__ xvb,
                                               const short* __restrict__ xtb,
                                               const short* __restrict__ wqb,
                                               const short* __restrict__ wkb,
                                               const short* __restrict__ wvb,
                                               short* __restrict__ qb,
                                               short* __restrict__ kbm,
                                               short* __restrict__ vbt) {
    __shared__ __align__(16) short As[64][72];
    __shared__ __align__(16) short Bs[64][72];
    int bx = blockIdx.x;
    const short* A; const short* BT; short* C; int m0; bool transC;
    if (bx < 64)      { A = xvb; BT = wqb; C = qb;  m0 = bx * 64;        transC = false; }
    else if (bx < 80) { A = xtb; BT = wkb; C = kbm; m0 = (bx - 64) * 64; transC = false; }
    else              { A = xtb; BT = wvb; C = vbt; m0 = (bx - 80) * 64; transC = true;  }
    int n0 = blockIdx.y * 64;
    int t = threadIdx.x;
    int lane = t & 63, w = t >> 6;
    int wr = w >> 1, wc = w & 1;
    int l15 = lane & 15, g = lane >> 4;

    f32x4 acc[2][2] = {};
    for (int kk = 0; kk < DMODEL; kk += 64) {
        {
            int row = t >> 2, c0 = (t & 3) * 16;
            *(short8*)&As[row][c0]     = *(const short8*)&A[(m0 + row) * DMODEL + kk + c0];
            *(short8*)&As[row][c0 + 8] = *(const short8*)&A[(m0 + row) * DMODEL + kk + c0 + 8];
            *(short8*)&Bs[row][c0]     = *(const short8*)&BT[(n0 + row) * DMODEL + kk + c0];
            *(short8*)&Bs[row][c0 + 8] = *(const short8*)&BT[(n0 + row) * DMODEL + kk + c0 + 8];
        }
        __syncthreads();
        #pragma unroll
        for (int ks = 0; ks < 2; ks++) {
            short8 a[2], b[2];
            #pragma unroll
            for (int fr = 0; fr < 2; fr++) a[fr] = *(short8*)&As[wr * 32 + fr * 16 + l15][ks * 32 + g * 8];
            #pragma unroll
            for (int fc = 0; fc < 2; fc++) b[fc] = *(short8*)&Bs[wc * 32 + fc * 16 + l15][ks * 32 + g * 8];
            #pragma unroll
            for (int fr = 0; fr < 2; fr++)
                #pragma unroll
                for (int fc = 0; fc < 2; fc++)
                    acc[fr][fc] = __builtin_amdgcn_mfma_f32_16x16x32_bf16(a[fr], b[fc], acc[fr][fc], 0, 0, 0);
        }
        __syncthreads();
    }
    #pragma unroll
    for (int fr = 0; fr < 2; fr++)
        #pragma unroll
        for (int fc = 0; fc < 2; fc++)
            #pragma unroll
            for (int r = 0; r < 4; r++) {
                int row = m0 + wr * 32 + fr * 16 + g * 4 + r;
                int col = n0 + wc * 32 + fc * 16 + l15;
                float v = acc[fr][fc][r];
                if (transC) C[col * M_TOK + row] = f2bf(v);
                else        C[row * DMODEL + col] = f2bf(v);
            }
}

// ---------------------------------------------------------------------------
// Final GEMM: out = Y * Wout(^T stored) + PE, fp32 out. 64x64 tile.
// ---------------------------------------------------------------------------
__global__ __launch_bounds__(256) void gemmOut(const short* __restrict__ A,
                                               const short* __restrict__ BT,
                                               float* __restrict__ Cout) {
    __shared__ __align__(16) short As[64][72];
    __shared__ __align__(16) short Bs[64][72];
    __shared__ float ifreq[256];
    int m0 = blockIdx.x * 64;
    int n0 = blockIdx.y * 64;
    int t = threadIdx.x;
    int lane = t & 63, w = t >> 6;
    int wr = w >> 1, wc = w & 1;
    int l15 = lane & 15, g = lane >> 4;

    ifreq[t] = expf(-(float)t * (9.210340371976184f / 512.0f));

    f32x4 acc[2][2] = {};
    for (int kk = 0; kk < DMODEL; kk += 64) {
        {
            int row = t >> 2, c0 = (t & 3) * 16;
            *(short8*)&As[row][c0]     = *(const short8*)&A[(m0 + row) * DMODEL + kk + c0];
            *(short8*)&As[row][c0 + 8] = *(const short8*)&A[(m0 + row) * DMODEL + kk + c0 + 8];
            *(short8*)&Bs[row][c0]     = *(const short8*)&BT[(n0 + row) * DMODEL + kk + c0];
            *(short8*)&Bs[row][c0 + 8] = *(const short8*)&BT[(n0 + row) * DMODEL + kk + c0 + 8];
        }
        __syncthreads();
        #pragma unroll
        for (int ks = 0; ks < 2; ks++) {
            short8 a[2], b[2];
            #pragma unroll
            for (int fr = 0; fr < 2; fr++) a[fr] = *(short8*)&As[wr * 32 + fr * 16 + l15][ks * 32 + g * 8];
            #pragma unroll
            for (int fc = 0; fc < 2; fc++) b[fc] = *(short8*)&Bs[wc * 32 + fc * 16 + l15][ks * 32 + g * 8];
            #pragma unroll
            for (int fr = 0; fr < 2; fr++)
                #pragma unroll
                for (int fc = 0; fc < 2; fc++)
                    acc[fr][fc] = __builtin_amdgcn_mfma_f32_16x16x32_bf16(a[fr], b[fc], acc[fr][fc], 0, 0, 0);
        }
        __syncthreads();
    }
    #pragma unroll
    for (int fr = 0; fr < 2; fr++)
        #pragma unroll
        for (int fc = 0; fc < 2; fc++)
            #pragma unroll
            for (int r = 0; r < 4; r++) {
                int row = m0 + wr * 32 + fr * 16 + g * 4 + r;
                int col = n0 + wc * 32 + fc * 16 + l15;
                float x = (float)row * ifreq[col >> 1];
                float pe = (col & 1) ? cosf(x) : sinf(x);
                Cout[row * DMODEL + col] = acc[fr][fc][r] + pe;
            }
}

// ---------------------------------------------------------------------------
// Attention v5: LDS-staged, double-buffered, XOR-swizzled.
// Block = 64 q x 1 head (4 waves x 16 q-rows, each wave ALL 1024 keys -> no
// merge). K tile [64 keys][64 d], V tile [64 d][64 keys] staged via
// global_load_lds(16B) with granule swizzle c ^= (row&7) applied on the
// GLOBAL source (LDS dest linear); ds_read_b128 applies the same swizzle.
// One barrier per 64-key tile. h = blockIdx.x & 7 pins each head to one XCD.
// ---------------------------------------------------------------------------
__global__ __launch_bounds__(256) void attn_kernel(const short* __restrict__ Qb,
                                                   const short* __restrict__ Kb,
                                                   const short* __restrict__ VbT,
                                                   short* __restrict__ Yb) {
    __shared__ __align__(16) short Ks[2][64][64];   // 16 KB
    __shared__ __align__(16) short Vs[2][64][64];   // 16 KB
    __shared__ __align__(16) short Ps[4][16][72];   // 9 KB (padded, ~2-way max)

    int bid = blockIdx.x;
    int h = bid & 7;               // XCD-pinned head
    int qx = bid >> 3;
    int n0 = qx * 64;
    int t = threadIdx.x;
    int lane = t & 63, w = t >> 6;
    int l15 = lane & 15, g = lane >> 4;

    const short* Kh  = Kb + h * DHEAD;                 // K[m][512]
    const short* VhT = VbT + (h * DHEAD) * M_TOK;      // V^T[d][1024]

    // staging geometry: per wave 2 instrs/tensor; lane -> row, swizzled granule
    int srow = (lane >> 3);                 // 0..7 within 8-row group
    int sgran = (lane & 7) ^ srow;          // source granule (involution)
    const short* gK0 = Kh + (size_t)(w * 16 + srow) * DMODEL + sgran * 8;
    const short* gV0 = VhT + (size_t)(w * 16 + srow) * M_TOK + sgran * 8;

    // Q fragments (loop-invariant, direct global)
    const short* qrow = Qb + (size_t)(n0 + w * 16 + l15) * DMODEL + h * DHEAD;
    short8 qa0 = *(const short8*)(qrow + g * 8);
    short8 qa1 = *(const short8*)(qrow + 32 + g * 8);

    f32x4 acc[4] = {};
    f32x4 rsum = {};
    int sx = l15 & 7;

    // prologue: stage tile 0 into buf 0
    {
        GLOAD_LDS16(gK0,                 &Ks[0][w * 16][0]);
        GLOAD_LDS16(gK0 + 8 * DMODEL,    &Ks[0][w * 16 + 8][0]);
        GLOAD_LDS16(gV0,                 &Vs[0][w * 16][0]);
        GLOAD_LDS16(gV0 + 8 * M_TOK,     &Vs[0][w * 16 + 8][0]);
    }
    __syncthreads();

    int buf = 0;
    for (int it = 0; it < 16; ++it) {
        // stage next tile into buf^1
        if (it < 15) {
            int key0 = (it + 1) * 64;
            GLOAD_LDS16(gK0 + (size_t)key0 * DMODEL,             &Ks[buf ^ 1][w * 16][0]);
            GLOAD_LDS16(gK0 + (size_t)(key0 + 8) * DMODEL,       &Ks[buf ^ 1][w * 16 + 8][0]);
            GLOAD_LDS16(gV0 + key0,                              &Vs[buf ^ 1][w * 16][0]);
            GLOAD_LDS16(gV0 + key0 + 8 * M_TOK,                  &Vs[buf ^ 1][w * 16 + 8][0]);
        }
        // QK^T over 64 keys: 4 subtiles of 16 keys
        #pragma unroll
        for (int kt = 0; kt < 4; kt++) {
            short8 kf0 = *(short8*)&Ks[buf][kt * 16 + l15][((g) ^ sx) * 8];
            short8 kf1 = *(short8*)&Ks[buf][kt * 16 + l15][((4 + g) ^ sx) * 8];
            f32x4 e = {};
            e = __builtin_amdgcn_mfma_f32_16x16x32_bf16(qa0, kf0, e, 0, 0, 0);
            e = __builtin_amdgcn_mfma_f32_16x16x32_bf16(qa1, kf1, e, 0, 0, 0);
            #pragma unroll
            for (int r = 0; r < 4; r++) {
                float p = exp2f(e[r] * 1.44269504f);
                rsum[r] += p;
                Ps[w][g * 4 + r][kt * 16 + l15] = f2bf(p);
            }
        }
        // PV over 64 keys: two 32-key halves
        #pragma unroll
        for (int kb2 = 0; kb2 < 2; kb2++) {
            short8 pa = *(short8*)&Ps[w][l15][kb2 * 32 + g * 8];
            #pragma unroll
            for (int nt = 0; nt < 4; nt++) {
                short8 vf = *(short8*)&Vs[buf][nt * 16 + l15][((kb2 * 4 + g) ^ sx) * 8];
                acc[nt] = __builtin_amdgcn_mfma_f32_16x16x32_bf16(pa, vf, acc[nt], 0, 0, 0);
            }
        }
        __syncthreads();      // drains stage (vmcnt) + protects buf reuse
        buf ^= 1;
    }

    // softmax denominator: reduce across the 16 l15-lanes of each g-group
    #pragma unroll
    for (int r = 0; r < 4; r++) {
        float s = rsum[r];
        s += __shfl_xor(s, 1);
        s += __shfl_xor(s, 2);
        s += __shfl_xor(s, 4);
        s += __shfl_xor(s, 8);
        rsum[r] = s;
    }

    #pragma unroll
    for (int nt = 0; nt < 4; nt++)
        #pragma unroll
        for (int r = 0; r < 4; r++) {
            float y = acc[nt][r] / rsum[r];
            Yb[(size_t)(n0 + w * 16 + g * 4 + r) * DMODEL + h * DHEAD + nt * 16 + l15] = f2bf(y);
        }
}

// ---------------------------------------------------------------------------
extern "C" void kernel_launch(void* const* d_in, const int* in_sizes, int n_in,
                              void* d_out, int out_size, void* d_ws, size_t ws_size,
                              hipStream_t stream) {
    const float* xv = (const float*)d_in[0];
    const float* xt = (const float*)d_in[1];
    const float* wq = (const float*)d_in[2];
    const float* wk = (const float*)d_in[3];
    const float* wv = (const float*)d_in[4];
    const float* wo = (const float*)d_in[5];

    short* xvb = (short*)d_ws;              // 4096*512
    short* xtb = xvb + N_TOK * DMODEL;      // 1024*512
    short* wqb = xtb + M_TOK * DMODEL;      // 512*512 (B^T)
    short* wkb = wqb + DMODEL * DMODEL;
    short* wvb = wkb + DMODEL * DMODEL;
    short* wob = wvb + DMODEL * DMODEL;
    short* qb  = wob + DMODEL * DMODEL;     // 4096*512
    short* kbm = qb  + N_TOK * DMODEL;      // 1024*512
    short* vbt = kbm + M_TOK * DMODEL;      // 512*1024 (V^T)
    short* yb  = vbt + M_TOK * DMODEL;      // 4096*512

    pack_kernel<<<1024, 256, 0, stream>>>(xv, xt, wq, wk, wv, wo,
                                          xvb, xtb, wqb, wkb, wvb, wob);
    gemmQKV<<<dim3(96, 8), 256, 0, stream>>>(xvb, xtb, wqb, wkb, wvb, qb, kbm, vbt);
    attn_kernel<<<512, 256, 0, stream>>>(qb, kbm, vbt, yb);
    gemmOut<<<dim3(N_TOK / 64, 8), 256, 0, stream>>>(yb, wob, (float*)d_out);
}